// Round 1
// baseline (26.157 us; speedup 1.0000x reference)
//
#include <hip/hip_runtime.h>

// out[b, i] = prod_{d=0..7} in[b, digit_d(i), d],  i = sum digit_d * 4^(7-d)
// B blocks, 256 threads each. head/tail prefix-product tables in LDS,
// then 64 coalesced float4 stores per thread.

__global__ __launch_bounds__(256) void rule_outer_kernel(
    const float* __restrict__ in, float* __restrict__ out) {
    const int b = blockIdx.x;
    const int t = threadIdx.x;

    __shared__ float x[32];      // x[m*8 + d], m in [0,4), d in [0,8)
    __shared__ float head[256];  // prod over d=0..3, index i0*64+i1*16+i2*4+i3
    __shared__ float tail[256];  // prod over d=4..7, index i4*64+i5*16+i6*4+i7

    if (t < 32) x[t] = in[b * 32 + t];
    __syncthreads();

    const int j0 = (t >> 6) & 3;
    const int j1 = (t >> 4) & 3;
    const int j2 = (t >> 2) & 3;
    const int j3 = t & 3;
    head[t] = x[j0 * 8 + 0] * x[j1 * 8 + 1] * x[j2 * 8 + 2] * x[j3 * 8 + 3];
    tail[t] = x[j0 * 8 + 4] * x[j1 * 8 + 5] * x[j2 * 8 + 6] * x[j3 * 8 + 7];
    __syncthreads();

    // float4-granular output: 16384 float4 per batch. float4 index f = v*256+t.
    // hi = f>>6 (head index, wave-uniform), lo4 = f&63 = t&63 (fixed per thread).
    const int lo4 = t & 63;
    const float4 tf = *reinterpret_cast<const float4*>(&tail[lo4 * 4]);
    float4* outv = reinterpret_cast<float4*>(out) + (size_t)b * 16384;

#pragma unroll 8
    for (int v = 0; v < 64; ++v) {
        const int f = v * 256 + t;
        const float h = head[f >> 6];
        outv[f] = make_float4(h * tf.x, h * tf.y, h * tf.z, h * tf.w);
    }
}

extern "C" void kernel_launch(void* const* d_in, const int* in_sizes, int n_in,
                              void* d_out, int out_size, void* d_ws, size_t ws_size,
                              hipStream_t stream) {
    const float* in = (const float*)d_in[0];
    float* out = (float*)d_out;
    const int B = in_sizes[0] / 32;  // B*M*D = B*32
    rule_outer_kernel<<<B, 256, 0, stream>>>(in, out);
}

// Round 2
// 25.675 us; speedup vs baseline: 1.0188x; 1.0188x over previous
//
#include <hip/hip_runtime.h>

// out[b, i] = prod_{d=0..7} in[b, digit_d(i), d],  i = sum digit_d * 4^(7-d)
// Grid: 4 blocks per batch element (2048 blocks), 256 threads each.
// head/tail prefix-product tables in LDS, then 16 coalesced float4
// stores per thread (each block owns a contiguous 64 KiB quarter).

__global__ __launch_bounds__(256) void rule_outer_kernel(
    const float* __restrict__ in, float* __restrict__ out) {
    const int bb = blockIdx.x;
    const int b = bb >> 2;       // batch element
    const int q = bb & 3;        // quarter of the 65536-wide output row
    const int t = threadIdx.x;

    __shared__ float x[32];      // x[m*8 + d], m in [0,4), d in [0,8)
    __shared__ float head[256];  // prod over d=0..3, index i0*64+i1*16+i2*4+i3
    __shared__ float tail[256];  // prod over d=4..7, index i4*64+i5*16+i6*4+i7

    if (t < 32) x[t] = in[b * 32 + t];
    __syncthreads();

    const int j0 = (t >> 6) & 3;
    const int j1 = (t >> 4) & 3;
    const int j2 = (t >> 2) & 3;
    const int j3 = t & 3;
    head[t] = x[j0 * 8 + 0] * x[j1 * 8 + 1] * x[j2 * 8 + 2] * x[j3 * 8 + 3];
    tail[t] = x[j0 * 8 + 4] * x[j1 * 8 + 5] * x[j2 * 8 + 6] * x[j3 * 8 + 7];
    __syncthreads();

    // Output row = 16384 float4. This block covers f in [q*4096, q*4096+4096).
    // f = q*4096 + v*256 + t; head index hi = f>>6 (wave-uniform);
    // tail float4 index = f&63 = t&63 (fixed per thread).
    const int lo4 = t & 63;
    const float4 tf = *reinterpret_cast<const float4*>(&tail[lo4 * 4]);
    float4* outv = reinterpret_cast<float4*>(out) + (size_t)b * 16384 + q * 4096;

#pragma unroll
    for (int v = 0; v < 16; ++v) {
        const int f = v * 256 + t;
        const float h = head[(q * 4096 + f) >> 6];
        outv[f] = make_float4(h * tf.x, h * tf.y, h * tf.z, h * tf.w);
    }
}

extern "C" void kernel_launch(void* const* d_in, const int* in_sizes, int n_in,
                              void* d_out, int out_size, void* d_ws, size_t ws_size,
                              hipStream_t stream) {
    const float* in = (const float*)d_in[0];
    float* out = (float*)d_out;
    const int B = in_sizes[0] / 32;  // B*M*D = B*32
    rule_outer_kernel<<<B * 4, 256, 0, stream>>>(in, out);
}